// Round 7
// baseline (151.268 us; speedup 1.0000x reference)
//
#include <hip/hip_runtime.h>
#include <hip/hip_bf16.h>

// Row-wise cosine hinge loss.
//   j = (i + 1 + neg_idx[i]) % B
//   hinge_i = relu(1 - cos(t_i, o_i) + cos(t_j, o_i))
//   out = sum_i hinge_i / B
//
// R7 strategy: LDS-staged streaming via global_load_lds DMA (width 16).
// Outstanding loads cost ZERO VGPRs, so the compiler cannot collapse them
// into a vmcnt convoy (the R4-R6 failure mode: VGPR_Count pinned at 32-48,
// ~3.5 KB/CU in flight, ~2.2 TB/s). Each wave owns a private 12 KB LDS
// region [o | t | t_neg]; 12 DMA instructions per row; vmcnt(0); consume
// via ds_read_b128 + FMA + DPP reduction. 4 waves/block x 12 KB = 48 KB
// -> 3 blocks/CU = 12 waves/CU with DMA in flight.

#define EPS 1e-6f

typedef float f4 __attribute__((ext_vector_type(4)));

// s_waitcnt immediates (gfx9 encoding: vm[3:0]|[15:14], exp[6:4], lgkm[11:8])
#define WAIT_VM0   0x0f70   // vmcnt(0), exp/lgkm no-wait
#define WAIT_LGKM0 0xc07f   // lgkmcnt(0), vm/exp no-wait

// VALU-pipe wave reduction via DPP; lane 63 holds the 64-lane sum.
#define DPP_STEP(x, ctrl, rm, bm)                                             \
    x += __int_as_float(__builtin_amdgcn_update_dpp(                          \
        0, __float_as_int(x), (ctrl), (rm), (bm), true))

__device__ __forceinline__ float dpp_wave_sum(float x) {
    DPP_STEP(x, 0x111, 0xf, 0xf);  // row_shr:1
    DPP_STEP(x, 0x112, 0xf, 0xf);  // row_shr:2
    DPP_STEP(x, 0x114, 0xf, 0xe);  // row_shr:4
    DPP_STEP(x, 0x118, 0xf, 0xc);  // row_shr:8
    DPP_STEP(x, 0x142, 0xa, 0xf);  // row_bcast:15
    DPP_STEP(x, 0x143, 0xc, 0xf);  // row_bcast:31
    return x;                      // valid in lane 63
}

// Async global->LDS DMA, 16 B/lane. g is per-lane (lane-contiguous);
// l is wave-uniform; HW writes lane's 16 B at l + lane*16.
__device__ __forceinline__ void dma16(const float* g, float* l) {
    __builtin_amdgcn_global_load_lds(
        (const __attribute__((address_space(1))) float*)g,
        (__attribute__((address_space(3))) float*)l,
        16, 0, 0);
}

__global__ __launch_bounds__(256, 3) void hinge_cos_kernel(
    const float* __restrict__ outm,   // [B, D]
    const float* __restrict__ tgt,    // [B, D]
    const int*   __restrict__ negidx, // [B]
    float* __restrict__ res,          // [1] scalar (pre-zeroed)
    int B, int D, float invB) {

    // Per-wave staging: [o: 1024 f][t: 1024 f][n: 1024 f] = 12 KB. 4 waves.
    __shared__ float stage[4][3072];
    __shared__ float red[4];

    const int lane  = threadIdx.x & 63;
    const int wave  = threadIdx.x >> 6;
    const int gwave = blockIdx.x * 4 + wave;
    const int nwav  = gridDim.x * 4;

    float* sw = &stage[wave][0];
    const f4* sv = (const f4*)sw;     // o: [0,256) t: [256,512) n: [512,768)

    float acc = 0.f;                  // per-wave hinge sum (lane 63)

    for (int i = gwave; i < B; i += nwav) {
        int j = i + 1 + negidx[i];
        if (j >= B) j -= B;

        const float* ob = outm + (size_t)i * D;
        const float* tb = tgt  + (size_t)i * D;
        const float* nb = tgt  + (size_t)j * D;

        // Previous row's ds_reads must be complete before DMA overwrites LDS.
        __builtin_amdgcn_s_waitcnt(WAIT_LGKM0);

        // 12 DMA issues: zero VGPR cost for in-flight data.
#pragma unroll
        for (int k = 0; k < 4; ++k) dma16(ob + k * 256 + lane * 4, sw + k * 256);
#pragma unroll
        for (int k = 0; k < 4; ++k) dma16(tb + k * 256 + lane * 4, sw + 1024 + k * 256);
#pragma unroll
        for (int k = 0; k < 4; ++k) dma16(nb + k * 256 + lane * 4, sw + 2048 + k * 256);

        // Drain the DMA queue, then consume from LDS.
        __builtin_amdgcn_s_waitcnt(WAIT_VM0);
        __builtin_amdgcn_sched_barrier(0);   // keep ds_reads below the wait

        float dto = 0.f, dno = 0.f, oo = 0.f, tt = 0.f, nn = 0.f;
#pragma unroll
        for (int k = 0; k < 4; ++k) {
            f4 o = sv[      k * 64 + lane];
            f4 t = sv[256 + k * 64 + lane];
            f4 n = sv[512 + k * 64 + lane];
            dto += o.x * t.x + o.y * t.y + o.z * t.z + o.w * t.w;
            dno += o.x * n.x + o.y * n.y + o.z * n.z + o.w * n.w;
            oo  += o.x * o.x + o.y * o.y + o.z * o.z + o.w * o.w;
            tt  += t.x * t.x + t.y * t.y + t.z * t.z + t.w * t.w;
            nn  += n.x * n.x + n.y * n.y + n.z * n.z + n.w * n.w;
        }

        dto = dpp_wave_sum(dto);
        dno = dpp_wave_sum(dno);
        oo  = dpp_wave_sum(oo);
        tt  = dpp_wave_sum(tt);
        nn  = dpp_wave_sum(nn);

        if (lane == 63) {
            float no = sqrtf(oo);
            float h  = 1.f - dto / fmaxf(sqrtf(tt) * no, EPS)
                           + dno / fmaxf(sqrtf(nn) * no, EPS);
            acc += fmaxf(h, 0.f);
        }
    }

    // Block-level: lane 63 of each wave holds its partial; one atomic/block.
    if (lane == 63) red[wave] = acc;
    __syncthreads();
    if (threadIdx.x == 0) {
        float s = 0.f;
#pragma unroll
        for (int w = 0; w < 4; ++w) s += red[w];
        atomicAdd(res, s * invB);
    }
}

extern "C" void kernel_launch(void* const* d_in, const int* in_sizes, int n_in,
                              void* d_out, int out_size, void* d_ws, size_t ws_size,
                              hipStream_t stream) {
    const float* outm   = (const float*)d_in[0];
    const float* tgt    = (const float*)d_in[1];
    const int*   negidx = (const int*)d_in[2];
    float* res = (float*)d_out;

    const int B = in_sizes[2];
    const int D = in_sizes[0] / B;

    (void)hipMemsetAsync(res, 0, sizeof(float), stream);

    // 768 blocks x 256 thr: 48 KB LDS/block -> 3 blocks/CU on 256 CUs,
    // 3072 waves, each grid-striding over 5-6 rows.
    hinge_cos_kernel<<<768, 256, 0, stream>>>(outm, tgt, negidx, res, B, D,
                                              1.0f / (float)B);
}